// Round 2
// baseline (533.593 us; speedup 1.0000x reference)
//
#include <hip/hip_runtime.h>

#define T_ 2048
#define C_ 1024
#define NH_ 16
#define HD_ 64
#define M_TOT 8192  // B*T

typedef __bf16 bf16x8 __attribute__((ext_vector_type(8)));
typedef float f32x4 __attribute__((ext_vector_type(4)));
typedef unsigned short ushort8 __attribute__((ext_vector_type(8)));

__device__ __forceinline__ unsigned short f2bf(float f) {
  union { float f; unsigned u; } v; v.f = f;
  unsigned r = v.u + 0x7fffu + ((v.u >> 16) & 1u);
  return (unsigned short)(r >> 16);
}
__device__ __forceinline__ __bf16 f2bf16(float f) {
  unsigned short u = f2bf(f);
  return __builtin_bit_cast(__bf16, u);
}

__device__ __forceinline__ void async16(const void* g, void* l) {
  __builtin_amdgcn_global_load_lds(
      (__attribute__((address_space(1))) void*)g,
      (__attribute__((address_space(3))) void*)l, 16, 0, 0);
}

// out[c][r] = bf16(in[r][c]); grid (Cc/32, R/32), 256 thr
__global__ void transpose_conv_k(const float* __restrict__ in,
                                 unsigned short* __restrict__ out, int R, int Cc) {
  __shared__ float tile[32][33];
  int c0 = blockIdx.x * 32, r0 = blockIdx.y * 32;
  int lx = threadIdx.x & 31, ly = threadIdx.x >> 5;
#pragma unroll
  for (int j = 0; j < 32; j += 8)
    tile[ly + j][lx] = in[(size_t)(r0 + ly + j) * Cc + c0 + lx];
  __syncthreads();
#pragma unroll
  for (int j = 0; j < 32; j += 8)
    out[(size_t)(c0 + ly + j) * R + r0 + lx] = f2bf(tile[lx][ly + j]);
}

// ---------------- GEMM1: qkv = x(f32) @ wqkvT^T + b; scatter Q,K (head-major)
// and V directly transposed [b,h,d,t]. 128x128 tile, BK=32, 4 waves.

__global__ __launch_bounds__(256, 2) void gemm_qkv(
    const float* __restrict__ X, const unsigned short* __restrict__ Bt,
    const float* __restrict__ bias, unsigned short* __restrict__ qw,
    unsigned short* __restrict__ kw, unsigned short* __restrict__ vtw) {
  __shared__ __align__(16) char laf[128 * 144];       // f32 A tile, padded rows (36 words)
  __shared__ __align__(16) unsigned short lb[128 * 32];  // bf16 B tile, linear (m97)
  const int tid = threadIdx.x, lane = tid & 63, wave = tid >> 6;
  const int wr = wave >> 1, wc = wave & 1;
  const int m0 = blockIdx.y * 128, n0 = blockIdx.x * 128;
  const int fr = lane & 15, fg = lane >> 4;
  const int r8 = tid >> 3, s8 = tid & 7;  // A stage: 8 slots x 16B per 128B row
  const int r4 = tid >> 2, s4 = tid & 3;  // B stage: 4 slots x 16B per 64B row

  f32x4 acc[4][4] = {};

  for (int k0 = 0; k0 < C_; k0 += 32) {
    // B tile via global_load_lds, LINEAR dest (= tid*16 within each half)
    async16(Bt + (size_t)(n0 + r4) * C_ + k0 + s4 * 8, (char*)lb + wave * 1024);
    async16(Bt + (size_t)(n0 + 64 + r4) * C_ + k0 + s4 * 8,
            (char*)lb + 4096 + wave * 1024);
    // A tile reg-staged (f32, padded rows to avoid bank conflicts)
#pragma unroll
    for (int c = 0; c < 4; c++) {
      int row = c * 32 + r8;
      f32x4 t = *(const f32x4*)(X + (size_t)(m0 + row) * C_ + k0 + s8 * 4);
      *(f32x4*)(laf + row * 144 + s8 * 16) = t;
    }
    __syncthreads();

    bf16x8 af[4], bfr[4];
#pragma unroll
    for (int mi = 0; mi < 4; mi++) {
      int row = wr * 64 + mi * 16 + fr;
      const float* ap = (const float*)(laf + row * 144) + fg * 8;
      f32x4 lo = *(const f32x4*)ap;
      f32x4 hi = *(const f32x4*)(ap + 4);
      bf16x8 a;
#pragma unroll
      for (int j = 0; j < 4; j++) { a[j] = f2bf16(lo[j]); a[4 + j] = f2bf16(hi[j]); }
      af[mi] = a;
    }
#pragma unroll
    for (int ni = 0; ni < 4; ni++) {
      int row = wc * 64 + ni * 16 + fr;
      bfr[ni] = *(const bf16x8*)((const char*)lb + row * 64 + fg * 16);
    }
#pragma unroll
    for (int mi = 0; mi < 4; mi++)
#pragma unroll
      for (int ni = 0; ni < 4; ni++)
        acc[mi][ni] = __builtin_amdgcn_mfma_f32_16x16x32_bf16(af[mi], bfr[ni],
                                                              acc[mi][ni], 0, 0, 0);
    __syncthreads();
  }

  // epilogue: C/D layout col=lane&15, row=(lane>>4)*4+r (m89-verified)
#pragma unroll
  for (int mi = 0; mi < 4; mi++)
#pragma unroll
    for (int ni = 0; ni < 4; ni++) {
      int col = n0 + wc * 64 + ni * 16 + fr;
      float bv = bias[col];
      int which = col >> 10, within = col & 1023;
      int h = within >> 6, hd = within & 63;
#pragma unroll
      for (int r = 0; r < 4; r++) {
        int row = m0 + wr * 64 + mi * 16 + fg * 4 + r;
        int b = row >> 11, t = row & 2047;
        unsigned short u = f2bf(acc[mi][ni][r] + bv);
        if (which == 0)
          qw[(((size_t)b * NH_ + h) * T_ + t) * HD_ + hd] = u;
        else if (which == 1)
          kw[(((size_t)b * NH_ + h) * T_ + t) * HD_ + hd] = u;
        else
          vtw[(((size_t)b * NH_ + h) * HD_ + hd) * T_ + t] = u;
      }
    }
}

// ---------------- flash attention: grid (T/64, B*NH), 256 thr, 4 waves.
// Reads Q/K head-major, V^T [b,h,d,t]; writes output OVER its own Q rows.

__global__ __launch_bounds__(256, 2) void attn_k(
    unsigned short* __restrict__ qws, const unsigned short* __restrict__ kws,
    const unsigned short* __restrict__ vtws) {
  __shared__ __align__(16) char kbuf[64 * 144];
  __shared__ __align__(16) char vbuf[64 * 144];
  __shared__ __align__(16) char pbuf[4 * 16 * 144];
  const int tid = threadIdx.x, lane = tid & 63, wave = tid >> 6;
  const int qb = blockIdx.x, bh = blockIdx.y;
  const int fr = lane & 15, fg = lane >> 4;
  unsigned short* qbase = qws + (size_t)bh * T_ * HD_;
  const unsigned short* kbase = kws + (size_t)bh * T_ * HD_;
  const unsigned short* vbase = vtws + (size_t)bh * HD_ * T_;  // [d][t]
  const int r0 = tid >> 3, sl = tid & 7;

  // Q fragments: direct global vector loads (block-exclusive rows)
  bf16x8 qf[2];
#pragma unroll
  for (int ks = 0; ks < 2; ks++)
    qf[ks] = *(const bf16x8*)(qbase + (size_t)(qb * 64 + wave * 16 + fr) * HD_ +
                              ks * 32 + fg * 8);

  f32x4 oacc[4] = {};
  float mrow[4] = {-1e30f, -1e30f, -1e30f, -1e30f};
  float lrow[4] = {0.f, 0.f, 0.f, 0.f};

  for (int kt = 0; kt <= qb; kt++) {
    // reg-staged K and V^T tiles into padded LDS
    {
      ushort8 ka = *(const ushort8*)(kbase + (size_t)(kt * 64 + r0) * HD_ + sl * 8);
      ushort8 kb2 = *(const ushort8*)(kbase + (size_t)(kt * 64 + 32 + r0) * HD_ + sl * 8);
      ushort8 va = *(const ushort8*)(vbase + (size_t)r0 * T_ + kt * 64 + sl * 8);
      ushort8 vb2 = *(const ushort8*)(vbase + (size_t)(32 + r0) * T_ + kt * 64 + sl * 8);
      *(ushort8*)(kbuf + r0 * 144 + sl * 16) = ka;
      *(ushort8*)(kbuf + (32 + r0) * 144 + sl * 16) = kb2;
      *(ushort8*)(vbuf + r0 * 144 + sl * 16) = va;
      *(ushort8*)(vbuf + (32 + r0) * 144 + sl * 16) = vb2;
    }
    __syncthreads();

    // S = Q K^T : s[ni] covers kv = ni*16+fr (col), q = wave*16 + fg*4+r (row)
    f32x4 s[4] = {};
#pragma unroll
    for (int ni = 0; ni < 4; ni++) {
#pragma unroll
      for (int ks = 0; ks < 2; ks++) {
        int chunk = ks * 4 + fg;
        bf16x8 kf = *(const bf16x8*)(kbuf + (ni * 16 + fr) * 144 + chunk * 16);
        s[ni] = __builtin_amdgcn_mfma_f32_16x16x32_bf16(qf[ks], kf, s[ni], 0, 0, 0);
      }
    }

    const bool diag = (kt == qb);
#pragma unroll
    for (int ni = 0; ni < 4; ni++)
#pragma unroll
      for (int r = 0; r < 4; r++) {
        float x = s[ni][r] * 0.125f;  // 1/sqrt(64)
        if (diag) {
          int colk = ni * 16 + fr;
          int rowq = wave * 16 + fg * 4 + r;
          if (colk > rowq) x = -1e30f;
        }
        s[ni][r] = x;
      }

    float scl[4];
#pragma unroll
    for (int r = 0; r < 4; r++) {
      float v = fmaxf(fmaxf(s[0][r], s[1][r]), fmaxf(s[2][r], s[3][r]));
#pragma unroll
      for (int off = 1; off < 16; off <<= 1) v = fmaxf(v, __shfl_xor(v, off, 64));
      float mn = fmaxf(mrow[r], v);
      scl[r] = __expf(mrow[r] - mn);
      mrow[r] = mn;
    }
#pragma unroll
    for (int r = 0; r < 4; r++) {
      float rs = 0.f;
#pragma unroll
      for (int ni = 0; ni < 4; ni++) {
        float p = __expf(s[ni][r] - mrow[r]);
        s[ni][r] = p;
        rs += p;
      }
#pragma unroll
      for (int off = 1; off < 16; off <<= 1) rs += __shfl_xor(rs, off, 64);
      lrow[r] = lrow[r] * scl[r] + rs;
#pragma unroll
      for (int di = 0; di < 4; di++) oacc[di][r] *= scl[r];
    }

    // P -> per-wave padded LDS, then PV
#pragma unroll
    for (int ni = 0; ni < 4; ni++)
#pragma unroll
      for (int r = 0; r < 4; r++) {
        int prow = fg * 4 + r;
        int cb = (ni * 16 + fr) * 2;
        *(unsigned short*)(pbuf + wave * 2304 + prow * 144 + cb) = f2bf(s[ni][r]);
      }
    __syncthreads();

#pragma unroll
    for (int ks = 0; ks < 2; ks++) {
      int chunk = ks * 4 + fg;
      bf16x8 pa = *(const bf16x8*)(pbuf + wave * 2304 + fr * 144 + chunk * 16);
#pragma unroll
      for (int di = 0; di < 4; di++) {
        bf16x8 vf = *(const bf16x8*)(vbuf + (di * 16 + fr) * 144 + chunk * 16);
        oacc[di] = __builtin_amdgcn_mfma_f32_16x16x32_bf16(pa, vf, oacc[di], 0, 0, 0);
      }
    }
    __syncthreads();
  }

  // write output over own Q rows (head-major [b,h,t,d])
#pragma unroll
  for (int di = 0; di < 4; di++)
#pragma unroll
    for (int r = 0; r < 4; r++) {
      int t = qb * 64 + wave * 16 + fg * 4 + r;
      int d = di * 16 + fr;
      qbase[(size_t)t * HD_ + d] = f2bf(oacc[di][r] / lrow[r]);
    }
}

// ---------------- GEMM2: out = attn(head-major bf16) @ wprojT^T + b_proj (f32)

__global__ __launch_bounds__(256, 2) void gemm_proj(
    const unsigned short* __restrict__ Ahm, const unsigned short* __restrict__ Bt,
    const float* __restrict__ bias, float* __restrict__ outf) {
  __shared__ __align__(16) unsigned short la[128 * 32];
  __shared__ __align__(16) unsigned short lb[128 * 32];
  const int tid = threadIdx.x, lane = tid & 63, wave = tid >> 6;
  const int wr = wave >> 1, wc = wave & 1;
  const int m0 = blockIdx.y * 128, n0 = blockIdx.x * 128;
  const int fr = lane & 15, fg = lane >> 4;
  const int r4 = tid >> 2, s4 = tid & 3;

  f32x4 acc[4][4] = {};

  for (int k0 = 0; k0 < C_; k0 += 32) {
    int head = k0 >> 6, off = k0 & 63;
    {
      int row = m0 + r4;
      async16(Ahm + (((size_t)(row >> 11) * NH_ + head) * T_ + (row & 2047)) * HD_ +
                  off + s4 * 8,
              (char*)la + wave * 1024);
      row = m0 + 64 + r4;
      async16(Ahm + (((size_t)(row >> 11) * NH_ + head) * T_ + (row & 2047)) * HD_ +
                  off + s4 * 8,
              (char*)la + 4096 + wave * 1024);
    }
    async16(Bt + (size_t)(n0 + r4) * C_ + k0 + s4 * 8, (char*)lb + wave * 1024);
    async16(Bt + (size_t)(n0 + 64 + r4) * C_ + k0 + s4 * 8,
            (char*)lb + 4096 + wave * 1024);
    __syncthreads();

    bf16x8 af[4], bfr[4];
#pragma unroll
    for (int mi = 0; mi < 4; mi++) {
      int row = wr * 64 + mi * 16 + fr;
      af[mi] = *(const bf16x8*)((const char*)la + row * 64 + fg * 16);
    }
#pragma unroll
    for (int ni = 0; ni < 4; ni++) {
      int row = wc * 64 + ni * 16 + fr;
      bfr[ni] = *(const bf16x8*)((const char*)lb + row * 64 + fg * 16);
    }
#pragma unroll
    for (int mi = 0; mi < 4; mi++)
#pragma unroll
      for (int ni = 0; ni < 4; ni++)
        acc[mi][ni] = __builtin_amdgcn_mfma_f32_16x16x32_bf16(af[mi], bfr[ni],
                                                              acc[mi][ni], 0, 0, 0);
    __syncthreads();
  }

#pragma unroll
  for (int mi = 0; mi < 4; mi++)
#pragma unroll
    for (int ni = 0; ni < 4; ni++) {
      int col = n0 + wc * 64 + ni * 16 + fr;
      float bv = bias[col];
#pragma unroll
      for (int r = 0; r < 4; r++) {
        int row = m0 + wr * 64 + mi * 16 + fg * 4 + r;
        outf[(size_t)row * C_ + col] = acc[mi][ni][r] + bv;
      }
    }
}

// ---------------- launch ----------------

extern "C" void kernel_launch(void* const* d_in, const int* in_sizes, int n_in,
                              void* d_out, int out_size, void* d_ws, size_t ws_size,
                              hipStream_t stream) {
  (void)in_sizes; (void)n_in; (void)out_size; (void)ws_size;
  const float* x      = (const float*)d_in[0];
  const float* w_attn = (const float*)d_in[1];
  const float* b_attn = (const float*)d_in[2];
  const float* w_proj = (const float*)d_in[3];
  const float* b_proj = (const float*)d_in[4];
  float* out = (float*)d_out;
  char* ws = (char*)d_ws;

  // ws layout, 56 MiB total:
  unsigned short* qws    = (unsigned short*)(ws);              // [b,h,t,d]; becomes attn out
  unsigned short* kws    = (unsigned short*)(ws + 16777216);   // [b,h,t,d]
  unsigned short* vtws   = (unsigned short*)(ws + 33554432);   // [b,h,d,t]
  unsigned short* wqkvT  = (unsigned short*)(ws + 50331648);   // [3072][1024] bf16
  unsigned short* wprojT = (unsigned short*)(ws + 56623104);   // [1024][1024] bf16

  transpose_conv_k<<<dim3(96, 32), 256, 0, stream>>>(w_attn, wqkvT, C_, 3 * C_);
  transpose_conv_k<<<dim3(32, 32), 256, 0, stream>>>(w_proj, wprojT, C_, C_);
  gemm_qkv<<<dim3(24, 64), 256, 0, stream>>>(x, wqkvT, b_attn, qws, kws, vtws);
  attn_k<<<dim3(32, 64), 256, 0, stream>>>(qws, kws, vtws);
  gemm_proj<<<dim3(8, 64), 256, 0, stream>>>(qws, wprojT, b_proj, out);
}

// Round 6
// 448.276 us; speedup vs baseline: 1.1903x; 1.1903x over previous
//
#include <hip/hip_runtime.h>

#define T_ 2048
#define C_ 1024
#define NH_ 16
#define HD_ 64
#define M_TOT 8192  // B*T

typedef __bf16 bf16x8 __attribute__((ext_vector_type(8)));
typedef float f32x4 __attribute__((ext_vector_type(4)));
typedef unsigned short ushort8 __attribute__((ext_vector_type(8)));

__device__ __forceinline__ unsigned short f2bf(float f) {
  union { float f; unsigned u; } v; v.f = f;
  unsigned r = v.u + 0x7fffu + ((v.u >> 16) & 1u);
  return (unsigned short)(r >> 16);
}

__device__ __forceinline__ void async16(const void* g, void* l) {
  __builtin_amdgcn_global_load_lds(
      (__attribute__((address_space(1))) void*)g,
      (__attribute__((address_space(3))) void*)l, 16, 0, 0);
}

// ---------------- prep kernels ----------------

__global__ void f32_to_bf16_k(const float* __restrict__ in,
                              unsigned short* __restrict__ out, int n) {
  int i = (blockIdx.x * blockDim.x + threadIdx.x) * 4;
  int stride = gridDim.x * blockDim.x * 4;
  for (; i < n; i += stride) {
    float4 v = *(const float4*)(in + i);
    ushort4 o;
    o.x = f2bf(v.x); o.y = f2bf(v.y); o.z = f2bf(v.z); o.w = f2bf(v.w);
    *(ushort4*)(out + i) = o;
  }
}

// out[c][r] = bf16(in[r][c]); grid (Cc/32, R/32), 256 thr
__global__ void transpose_conv_k(const float* __restrict__ in,
                                 unsigned short* __restrict__ out, int R, int Cc) {
  __shared__ float tile[32][33];
  int c0 = blockIdx.x * 32, r0 = blockIdx.y * 32;
  int lx = threadIdx.x & 31, ly = threadIdx.x >> 5;
#pragma unroll
  for (int j = 0; j < 32; j += 8)
    tile[ly + j][lx] = in[(size_t)(r0 + ly + j) * Cc + c0 + lx];
  __syncthreads();
#pragma unroll
  for (int j = 0; j < 32; j += 8)
    out[(size_t)(c0 + ly + j) * R + r0 + lx] = f2bf(tile[lx][ly + j]);
}

// ---------------- GEMM1: qkv = xb(bf16) @ wqkvT^T + b; scatter Q,K (head-major)
// and V transposed [b,h,d,t]. Pure m97: both operands via global_load_lds.

__global__ __launch_bounds__(256, 2) void gemm_qkv(
    const unsigned short* __restrict__ A, const unsigned short* __restrict__ Bt,
    const float* __restrict__ bias, unsigned short* __restrict__ qw,
    unsigned short* __restrict__ kw, unsigned short* __restrict__ vtw) {
  __shared__ __align__(16) unsigned short la[128 * 32];
  __shared__ __align__(16) unsigned short lb[128 * 32];
  const int tid = threadIdx.x, lane = tid & 63, wave = tid >> 6;
  const int wr = wave >> 1, wc = wave & 1;
  const int m0 = blockIdx.y * 128, n0 = blockIdx.x * 128;
  const int fr = lane & 15, fg = lane >> 4;
  const int r4 = tid >> 2, s4 = tid & 3;

  f32x4 acc[4][4] = {};

  for (int k0 = 0; k0 < C_; k0 += 32) {
    async16(A + (size_t)(m0 + r4) * C_ + k0 + s4 * 8, (char*)la + wave * 1024);
    async16(A + (size_t)(m0 + 64 + r4) * C_ + k0 + s4 * 8,
            (char*)la + 4096 + wave * 1024);
    async16(Bt + (size_t)(n0 + r4) * C_ + k0 + s4 * 8, (char*)lb + wave * 1024);
    async16(Bt + (size_t)(n0 + 64 + r4) * C_ + k0 + s4 * 8,
            (char*)lb + 4096 + wave * 1024);
    __syncthreads();

    bf16x8 af[4], bfr[4];
#pragma unroll
    for (int mi = 0; mi < 4; mi++) {
      int row = wr * 64 + mi * 16 + fr;
      af[mi] = *(const bf16x8*)((const char*)la + row * 64 + fg * 16);
    }
#pragma unroll
    for (int ni = 0; ni < 4; ni++) {
      int row = wc * 64 + ni * 16 + fr;
      bfr[ni] = *(const bf16x8*)((const char*)lb + row * 64 + fg * 16);
    }
#pragma unroll
    for (int mi = 0; mi < 4; mi++)
#pragma unroll
      for (int ni = 0; ni < 4; ni++)
        acc[mi][ni] = __builtin_amdgcn_mfma_f32_16x16x32_bf16(af[mi], bfr[ni],
                                                              acc[mi][ni], 0, 0, 0);
    __syncthreads();
  }

  // epilogue: C/D layout col=lane&15, row=(lane>>4)*4+r (m89-verified)
#pragma unroll
  for (int mi = 0; mi < 4; mi++)
#pragma unroll
    for (int ni = 0; ni < 4; ni++) {
      int col = n0 + wc * 64 + ni * 16 + fr;
      float bv = bias[col];
      int which = col >> 10, within = col & 1023;
      int h = within >> 6, hd = within & 63;
#pragma unroll
      for (int r = 0; r < 4; r++) {
        int row = m0 + wr * 64 + mi * 16 + fg * 4 + r;
        int b = row >> 11, t = row & 2047;
        unsigned short u = f2bf(acc[mi][ni][r] + bv);
        if (which == 0)
          qw[(((size_t)b * NH_ + h) * T_ + t) * HD_ + hd] = u;
        else if (which == 1)
          kw[(((size_t)b * NH_ + h) * T_ + t) * HD_ + hd] = u;
        else
          vtw[(((size_t)b * NH_ + h) * HD_ + hd) * T_ + t] = u;
      }
    }
}

// ---------------- flash attention: grid (T/128, B*NH), 256 thr, 4 waves.
// QBLK=128 (wave owns 32 q-rows), KVBLK=64. Output written over own Q rows.

__global__ __launch_bounds__(256, 2) void attn_k(
    unsigned short* __restrict__ qws, const unsigned short* __restrict__ kws,
    const unsigned short* __restrict__ vtws) {
  __shared__ __align__(16) char kbuf[64 * 144];
  __shared__ __align__(16) char vbuf[64 * 144];
  __shared__ __align__(16) char pbuf[4 * 32 * 144];
  const int tid = threadIdx.x, lane = tid & 63, wave = tid >> 6;
  const int qb = (int)gridDim.x - 1 - (int)blockIdx.x;  // LPT: longest first
  const int bh = blockIdx.y;
  const int fr = lane & 15, fg = lane >> 4;
  unsigned short* qbase = qws + (size_t)bh * T_ * HD_;
  const unsigned short* kbase = kws + (size_t)bh * T_ * HD_;
  const unsigned short* vbase = vtws + (size_t)bh * HD_ * T_;  // [d][t]
  const int r0 = tid >> 3, sl = tid & 7;

  // Q fragments: direct global vector loads (block-exclusive rows)
  bf16x8 qf[2][2];
#pragma unroll
  for (int mi = 0; mi < 2; mi++)
#pragma unroll
    for (int ks = 0; ks < 2; ks++)
      qf[mi][ks] = *(const bf16x8*)(
          qbase + (size_t)(qb * 128 + wave * 32 + mi * 16 + fr) * HD_ + ks * 32 +
          fg * 8);

  f32x4 oacc[2][4] = {};
  float mrow[2][4], lrow[2][4];
#pragma unroll
  for (int mi = 0; mi < 2; mi++)
#pragma unroll
    for (int r = 0; r < 4; r++) { mrow[mi][r] = -1e30f; lrow[mi][r] = 0.f; }

  int rowq[2][4];
#pragma unroll
  for (int mi = 0; mi < 2; mi++)
#pragma unroll
    for (int r = 0; r < 4; r++)
      rowq[mi][r] = qb * 128 + wave * 32 + mi * 16 + fg * 4 + r;

  const float SC = 0.125f * 1.44269504f;  // 1/sqrt(64) * log2(e)
  const int ktmax = 2 * qb + 1;

  for (int kt = 0; kt <= ktmax; kt++) {
    {
      ushort8 ka = *(const ushort8*)(kbase + (size_t)(kt * 64 + r0) * HD_ + sl * 8);
      ushort8 kb2 = *(const ushort8*)(kbase + (size_t)(kt * 64 + 32 + r0) * HD_ + sl * 8);
      ushort8 va = *(const ushort8*)(vbase + (size_t)r0 * T_ + kt * 64 + sl * 8);
      ushort8 vb2 = *(const ushort8*)(vbase + (size_t)(32 + r0) * T_ + kt * 64 + sl * 8);
      *(ushort8*)(kbuf + r0 * 144 + sl * 16) = ka;
      *(ushort8*)(kbuf + (32 + r0) * 144 + sl * 16) = kb2;
      *(ushort8*)(vbuf + r0 * 144 + sl * 16) = va;
      *(ushort8*)(vbuf + (32 + r0) * 144 + sl * 16) = vb2;
    }
    __syncthreads();

    // S = Q K^T (in log2 domain after scaling)
    f32x4 s[2][4] = {};
#pragma unroll
    for (int ni = 0; ni < 4; ni++)
#pragma unroll
      for (int ks = 0; ks < 2; ks++) {
        bf16x8 kf = *(const bf16x8*)(kbuf + (ni * 16 + fr) * 144 + (ks * 4 + fg) * 16);
#pragma unroll
        for (int mi = 0; mi < 2; mi++)
          s[mi][ni] = __builtin_amdgcn_mfma_f32_16x16x32_bf16(qf[mi][ks], kf,
                                                              s[mi][ni], 0, 0, 0);
      }

    const bool diag = (kt >= 2 * qb);
#pragma unroll
    for (int mi = 0; mi < 2; mi++)
#pragma unroll
      for (int ni = 0; ni < 4; ni++)
#pragma unroll
        for (int r = 0; r < 4; r++) {
          float x = s[mi][ni][r] * SC;
          if (diag) {
            int colk = kt * 64 + ni * 16 + fr;
            if (colk > rowq[mi][r]) x = -1e30f;
          }
          s[mi][ni][r] = x;
        }

#pragma unroll
    for (int mi = 0; mi < 2; mi++)
#pragma unroll
      for (int r = 0; r < 4; r++) {
        float v = fmaxf(fmaxf(s[mi][0][r], s[mi][1][r]),
                        fmaxf(s[mi][2][r], s[mi][3][r]));
#pragma unroll
        for (int off = 1; off < 16; off <<= 1) v = fmaxf(v, __shfl_xor(v, off, 64));
        float mn = fmaxf(mrow[mi][r], v);
        float scl = exp2f(mrow[mi][r] - mn);
        mrow[mi][r] = mn;
        float rs = 0.f;
#pragma unroll
        for (int ni = 0; ni < 4; ni++) {
          float p = exp2f(s[mi][ni][r] - mn);
          s[mi][ni][r] = p;
          rs += p;
        }
#pragma unroll
        for (int off = 1; off < 16; off <<= 1) rs += __shfl_xor(rs, off, 64);
        lrow[mi][r] = lrow[mi][r] * scl + rs;
#pragma unroll
        for (int di = 0; di < 4; di++) oacc[mi][di][r] *= scl;
      }

    // P -> per-wave padded LDS, then PV
#pragma unroll
    for (int mi = 0; mi < 2; mi++)
#pragma unroll
      for (int ni = 0; ni < 4; ni++)
#pragma unroll
        for (int r = 0; r < 4; r++) {
          int prow = mi * 16 + fg * 4 + r;
          int cb = (ni * 16 + fr) * 2;
          *(unsigned short*)(pbuf + wave * 4608 + prow * 144 + cb) =
              f2bf(s[mi][ni][r]);
        }
    __syncthreads();

#pragma unroll
    for (int ks = 0; ks < 2; ks++) {
      int chunk = ks * 4 + fg;
      bf16x8 pa[2];
#pragma unroll
      for (int mi = 0; mi < 2; mi++)
        pa[mi] = *(const bf16x8*)(pbuf + wave * 4608 + (mi * 16 + fr) * 144 +
                                  chunk * 16);
#pragma unroll
      for (int di = 0; di < 4; di++) {
        bf16x8 vf = *(const bf16x8*)(vbuf + (di * 16 + fr) * 144 + chunk * 16);
#pragma unroll
        for (int mi = 0; mi < 2; mi++)
          oacc[mi][di] = __builtin_amdgcn_mfma_f32_16x16x32_bf16(pa[mi], vf,
                                                                 oacc[mi][di], 0, 0, 0);
      }
    }
    __syncthreads();
  }

  // write output over own Q rows (head-major [b,h,t,d])
#pragma unroll
  for (int mi = 0; mi < 2; mi++)
#pragma unroll
    for (int di = 0; di < 4; di++)
#pragma unroll
      for (int r = 0; r < 4; r++) {
        int t = qb * 128 + wave * 32 + mi * 16 + fg * 4 + r;
        int d = di * 16 + fr;
        qbase[(size_t)t * HD_ + d] = f2bf(oacc[mi][di][r] / lrow[mi][r]);
      }
}

// ---------------- GEMM2: out = attn(head-major bf16) @ wprojT^T + b_proj (f32)

__global__ __launch_bounds__(256, 2) void gemm_proj(
    const unsigned short* __restrict__ Ahm, const unsigned short* __restrict__ Bt,
    const float* __restrict__ bias, float* __restrict__ outf) {
  __shared__ __align__(16) unsigned short la[128 * 32];
  __shared__ __align__(16) unsigned short lb[128 * 32];
  const int tid = threadIdx.x, lane = tid & 63, wave = tid >> 6;
  const int wr = wave >> 1, wc = wave & 1;
  const int m0 = blockIdx.y * 128, n0 = blockIdx.x * 128;
  const int fr = lane & 15, fg = lane >> 4;
  const int r4 = tid >> 2, s4 = tid & 3;

  f32x4 acc[4][4] = {};

  for (int k0 = 0; k0 < C_; k0 += 32) {
    int head = k0 >> 6, off = k0 & 63;
    {
      int row = m0 + r4;
      async16(Ahm + (((size_t)(row >> 11) * NH_ + head) * T_ + (row & 2047)) * HD_ +
                  off + s4 * 8,
              (char*)la + wave * 1024);
      row = m0 + 64 + r4;
      async16(Ahm + (((size_t)(row >> 11) * NH_ + head) * T_ + (row & 2047)) * HD_ +
                  off + s4 * 8,
              (char*)la + 4096 + wave * 1024);
    }
    async16(Bt + (size_t)(n0 + r4) * C_ + k0 + s4 * 8, (char*)lb + wave * 1024);
    async16(Bt + (size_t)(n0 + 64 + r4) * C_ + k0 + s4 * 8,
            (char*)lb + 4096 + wave * 1024);
    __syncthreads();

    bf16x8 af[4], bfr[4];
#pragma unroll
    for (int mi = 0; mi < 4; mi++) {
      int row = wr * 64 + mi * 16 + fr;
      af[mi] = *(const bf16x8*)((const char*)la + row * 64 + fg * 16);
    }
#pragma unroll
    for (int ni = 0; ni < 4; ni++) {
      int row = wc * 64 + ni * 16 + fr;
      bfr[ni] = *(const bf16x8*)((const char*)lb + row * 64 + fg * 16);
    }
#pragma unroll
    for (int mi = 0; mi < 4; mi++)
#pragma unroll
      for (int ni = 0; ni < 4; ni++)
        acc[mi][ni] = __builtin_amdgcn_mfma_f32_16x16x32_bf16(af[mi], bfr[ni],
                                                              acc[mi][ni], 0, 0, 0);
    __syncthreads();
  }

#pragma unroll
  for (int mi = 0; mi < 4; mi++)
#pragma unroll
    for (int ni = 0; ni < 4; ni++) {
      int col = n0 + wc * 64 + ni * 16 + fr;
      float bv = bias[col];
#pragma unroll
      for (int r = 0; r < 4; r++) {
        int row = m0 + wr * 64 + mi * 16 + fg * 4 + r;
        outf[(size_t)row * C_ + col] = acc[mi][ni][r] + bv;
      }
    }
}

// ---------------- launch ----------------

extern "C" void kernel_launch(void* const* d_in, const int* in_sizes, int n_in,
                              void* d_out, int out_size, void* d_ws, size_t ws_size,
                              hipStream_t stream) {
  (void)in_sizes; (void)n_in; (void)out_size;
  const float* x      = (const float*)d_in[0];
  const float* w_attn = (const float*)d_in[1];
  const float* b_attn = (const float*)d_in[2];
  const float* w_proj = (const float*)d_in[3];
  const float* b_proj = (const float*)d_in[4];
  float* out = (float*)d_out;
  char* ws = (char*)d_ws;

  // ws layout, 58.7 MiB base:
  unsigned short* qws    = (unsigned short*)(ws);              // [b,h,t,d]; becomes attn out
  unsigned short* kws    = (unsigned short*)(ws + 16777216);   // [b,h,t,d]
  unsigned short* vtws   = (unsigned short*)(ws + 33554432);   // [b,h,d,t]
  unsigned short* wqkvT  = (unsigned short*)(ws + 50331648);   // [3072][1024] bf16
  unsigned short* wprojT = (unsigned short*)(ws + 56623104);   // [1024][1024] bf16
  // xb (x as bf16, 16.8 MB): ws tail if it fits, else scratch inside d_out
  // (d_out is fully overwritten by gemm_proj at the end; stream-ordered).
  size_t xb_off = 58720256;
  unsigned short* xb = (ws_size >= xb_off + (size_t)M_TOT * C_ * 2)
                           ? (unsigned short*)(ws + xb_off)
                           : (unsigned short*)d_out;

  f32_to_bf16_k<<<2048, 256, 0, stream>>>(x, xb, M_TOT * C_);
  transpose_conv_k<<<dim3(96, 32), 256, 0, stream>>>(w_attn, wqkvT, C_, 3 * C_);
  transpose_conv_k<<<dim3(32, 32), 256, 0, stream>>>(w_proj, wprojT, C_, C_);
  gemm_qkv<<<dim3(24, 64), 256, 0, stream>>>(xb, wqkvT, b_attn, qws, kws, vtws);
  attn_k<<<dim3(16, 64), 256, 0, stream>>>(qws, kws, vtws);
  gemm_proj<<<dim3(8, 64), 256, 0, stream>>>(qws, wprojT, b_proj, out);
}

// Round 7
// 370.212 us; speedup vs baseline: 1.4413x; 1.2109x over previous
//
#include <hip/hip_runtime.h>

#define T_ 2048
#define C_ 1024
#define NH_ 16
#define HD_ 64
#define M_TOT 8192  // B*T

typedef __bf16 bf16x8 __attribute__((ext_vector_type(8)));
typedef float f32x4 __attribute__((ext_vector_type(4)));
typedef unsigned short ushort8 __attribute__((ext_vector_type(8)));
typedef unsigned int uint4v __attribute__((ext_vector_type(4)));

__device__ __forceinline__ unsigned short f2bf(float f) {
  union { float f; unsigned u; } v; v.f = f;
  unsigned r = v.u + 0x7fffu + ((v.u >> 16) & 1u);
  return (unsigned short)(r >> 16);
}

__device__ __forceinline__ void async16(const void* g, void* l) {
  __builtin_amdgcn_global_load_lds(
      (__attribute__((address_space(1))) void*)g,
      (__attribute__((address_space(3))) void*)l, 16, 0, 0);
}

// pack two f32 -> dword of 2 bf16 (lo in bits[15:0])
__device__ __forceinline__ unsigned cvt_pk_bf16(float lo, float hi) {
  unsigned d;
  asm volatile("v_cvt_pk_bf16_f32 %0, %1, %2" : "=v"(d) : "v"(lo), "v"(hi));
  return d;
}

// ---------------- prep kernels ----------------

__global__ void f32_to_bf16_k(const float* __restrict__ in,
                              unsigned short* __restrict__ out, int n) {
  int i = (blockIdx.x * blockDim.x + threadIdx.x) * 4;
  int stride = gridDim.x * blockDim.x * 4;
  for (; i < n; i += stride) {
    float4 v = *(const float4*)(in + i);
    ushort4 o;
    o.x = f2bf(v.x); o.y = f2bf(v.y); o.z = f2bf(v.z); o.w = f2bf(v.w);
    *(ushort4*)(out + i) = o;
  }
}

// out[c][r] = bf16(in[r][c]); grid (Cc/32, R/32), 256 thr
__global__ void transpose_conv_k(const float* __restrict__ in,
                                 unsigned short* __restrict__ out, int R, int Cc) {
  __shared__ float tile[32][33];
  int c0 = blockIdx.x * 32, r0 = blockIdx.y * 32;
  int lx = threadIdx.x & 31, ly = threadIdx.x >> 5;
#pragma unroll
  for (int j = 0; j < 32; j += 8)
    tile[ly + j][lx] = in[(size_t)(r0 + ly + j) * Cc + c0 + lx];
  __syncthreads();
#pragma unroll
  for (int j = 0; j < 32; j += 8)
    out[(size_t)(c0 + ly + j) * R + r0 + lx] = f2bf(tile[lx][ly + j]);
}

// ---------------- GEMM1: qkv = xb(bf16) @ wqkvT^T + b; scatter Q,K (head-major)
// and V transposed [b,h,d,t]. Pure m97: both operands via global_load_lds.

__global__ __launch_bounds__(256, 2) void gemm_qkv(
    const unsigned short* __restrict__ A, const unsigned short* __restrict__ Bt,
    const float* __restrict__ bias, unsigned short* __restrict__ qw,
    unsigned short* __restrict__ kw, unsigned short* __restrict__ vtw) {
  __shared__ __align__(16) unsigned short la[128 * 32];
  __shared__ __align__(16) unsigned short lb[128 * 32];
  const int tid = threadIdx.x, lane = tid & 63, wave = tid >> 6;
  const int wr = wave >> 1, wc = wave & 1;
  const int m0 = blockIdx.y * 128, n0 = blockIdx.x * 128;
  const int fr = lane & 15, fg = lane >> 4;
  const int r4 = tid >> 2, s4 = tid & 3;

  f32x4 acc[4][4] = {};

  for (int k0 = 0; k0 < C_; k0 += 32) {
    async16(A + (size_t)(m0 + r4) * C_ + k0 + s4 * 8, (char*)la + wave * 1024);
    async16(A + (size_t)(m0 + 64 + r4) * C_ + k0 + s4 * 8,
            (char*)la + 4096 + wave * 1024);
    async16(Bt + (size_t)(n0 + r4) * C_ + k0 + s4 * 8, (char*)lb + wave * 1024);
    async16(Bt + (size_t)(n0 + 64 + r4) * C_ + k0 + s4 * 8,
            (char*)lb + 4096 + wave * 1024);
    __syncthreads();

    bf16x8 af[4], bfr[4];
#pragma unroll
    for (int mi = 0; mi < 4; mi++) {
      int row = wr * 64 + mi * 16 + fr;
      af[mi] = *(const bf16x8*)((const char*)la + row * 64 + fg * 16);
    }
#pragma unroll
    for (int ni = 0; ni < 4; ni++) {
      int row = wc * 64 + ni * 16 + fr;
      bfr[ni] = *(const bf16x8*)((const char*)lb + row * 64 + fg * 16);
    }
#pragma unroll
    for (int mi = 0; mi < 4; mi++)
#pragma unroll
      for (int ni = 0; ni < 4; ni++)
        acc[mi][ni] = __builtin_amdgcn_mfma_f32_16x16x32_bf16(af[mi], bfr[ni],
                                                              acc[mi][ni], 0, 0, 0);
    __syncthreads();
  }

  // epilogue: C/D layout col=lane&15, row=(lane>>4)*4+r (m89-verified)
#pragma unroll
  for (int mi = 0; mi < 4; mi++)
#pragma unroll
    for (int ni = 0; ni < 4; ni++) {
      int col = n0 + wc * 64 + ni * 16 + fr;
      float bv = bias[col];
      int which = col >> 10, within = col & 1023;
      int h = within >> 6, hd = within & 63;
#pragma unroll
      for (int r = 0; r < 4; r++) {
        int row = m0 + wr * 64 + mi * 16 + fg * 4 + r;
        int b = row >> 11, t = row & 2047;
        unsigned short u = f2bf(acc[mi][ni][r] + bv);
        if (which == 0)
          qw[(((size_t)b * NH_ + h) * T_ + t) * HD_ + hd] = u;
        else if (which == 1)
          kw[(((size_t)b * NH_ + h) * T_ + t) * HD_ + hd] = u;
        else
          vtw[(((size_t)b * NH_ + h) * HD_ + hd) * T_ + t] = u;
      }
    }
}

// ---------------- flash attention (swapped-operand): grid (T/128, B*NH), 4 waves.
// S^T = mfma(K,Q): lane owns q-col -> softmax is in-register (2 shfls).
// P stays in registers (cvt_pk + ds_bpermute rebuild); PV: O^T = mfma(V^T, P^T).

__global__ __launch_bounds__(256, 2) void attn_k(
    unsigned short* __restrict__ qws, const unsigned short* __restrict__ kws,
    const unsigned short* __restrict__ vtws) {
  __shared__ __align__(16) char kbuf[64 * 144];
  __shared__ __align__(16) char vbuf[64 * 144];
  const int tid = threadIdx.x, lane = tid & 63, wave = tid >> 6;
  const int qb = (int)gridDim.x - 1 - (int)blockIdx.x;  // LPT: longest first
  const int bh = blockIdx.y;
  const int fr = lane & 15, fg = lane >> 4;
  unsigned short* qbase = qws + (size_t)bh * T_ * HD_;
  const unsigned short* kbase = kws + (size_t)bh * T_ * HD_;
  const unsigned short* vbase = vtws + (size_t)bh * HD_ * T_;  // [d][t]
  const int r0 = tid >> 3, sl = tid & 7;

  // Q fragments (B-operand: col=q=fr, k=d chunk fg)
  bf16x8 qf[2][2];
#pragma unroll
  for (int mi = 0; mi < 2; mi++)
#pragma unroll
    for (int ks = 0; ks < 2; ks++)
      qf[mi][ks] = *(const bf16x8*)(
          qbase + (size_t)(qb * 128 + wave * 32 + mi * 16 + fr) * HD_ + ks * 32 +
          fg * 8);

  // per-lane q rows (one per mi)
  int qrow[2];
#pragma unroll
  for (int mi = 0; mi < 2; mi++) qrow[mi] = qb * 128 + wave * 32 + mi * 16 + fr;

  f32x4 oacc[2][4] = {};                 // O^T: col=q=fr, row d = di*16+fg*4+r
  float mrow[2] = {-1e30f, -1e30f};
  float lrow[2] = {0.f, 0.f};

  const float SC = 0.125f * 1.44269504f;  // 1/sqrt(64) * log2(e)
  const int ktmax = 2 * qb + 1;

  // bpermute addresses for P^T fragment rebuild
  const int addr0 = (fr + 16 * ((2 * fg) & 3)) * 4;
  const int addr1 = (fr + 16 * ((2 * fg + 1) & 3)) * 4;
  const bool hiSel = (fg >> 1) != 0;

  // register prefetch of K/V tile (T14)
  ushort8 ka, kb2, va, vb2;
  {
    ka  = *(const ushort8*)(kbase + (size_t)(0 * 64 + r0) * HD_ + sl * 8);
    kb2 = *(const ushort8*)(kbase + (size_t)(0 * 64 + 32 + r0) * HD_ + sl * 8);
    va  = *(const ushort8*)(vbase + (size_t)r0 * T_ + 0 * 64 + sl * 8);
    vb2 = *(const ushort8*)(vbase + (size_t)(32 + r0) * T_ + 0 * 64 + sl * 8);
  }

  for (int kt = 0; kt <= ktmax; kt++) {
    // write staged regs to LDS
    *(ushort8*)(kbuf + r0 * 144 + sl * 16) = ka;
    *(ushort8*)(kbuf + (32 + r0) * 144 + sl * 16) = kb2;
    *(ushort8*)(vbuf + r0 * 144 + sl * 16) = va;
    *(ushort8*)(vbuf + (32 + r0) * 144 + sl * 16) = vb2;
    __syncthreads();

    // issue next tile's loads (hidden under compute)
    if (kt < ktmax) {
      int kn = kt + 1;
      ka  = *(const ushort8*)(kbase + (size_t)(kn * 64 + r0) * HD_ + sl * 8);
      kb2 = *(const ushort8*)(kbase + (size_t)(kn * 64 + 32 + r0) * HD_ + sl * 8);
      va  = *(const ushort8*)(vbase + (size_t)r0 * T_ + kn * 64 + sl * 8);
      vb2 = *(const ushort8*)(vbase + (size_t)(32 + r0) * T_ + kn * 64 + sl * 8);
    }

    // S^T = K Q^T : s[mi][ni][r] = S[kv = ni*16+fg*4+r][q = qrow[mi]]
    f32x4 s[2][4] = {};
#pragma unroll
    for (int ni = 0; ni < 4; ni++)
#pragma unroll
      for (int ks = 0; ks < 2; ks++) {
        bf16x8 kf = *(const bf16x8*)(kbuf + (ni * 16 + fr) * 144 + (ks * 4 + fg) * 16);
#pragma unroll
        for (int mi = 0; mi < 2; mi++)
          s[mi][ni] = __builtin_amdgcn_mfma_f32_16x16x32_bf16(kf, qf[mi][ks],
                                                              s[mi][ni], 0, 0, 0);
      }

    // scale (+ causal mask on diagonal tiles)
#pragma unroll
    for (int mi = 0; mi < 2; mi++)
#pragma unroll
      for (int ni = 0; ni < 4; ni++)
#pragma unroll
        for (int r = 0; r < 4; r++) s[mi][ni][r] *= SC;
    if (kt >= 2 * qb) {
#pragma unroll
      for (int mi = 0; mi < 2; mi++)
#pragma unroll
        for (int ni = 0; ni < 4; ni++)
#pragma unroll
          for (int r = 0; r < 4; r++) {
            int kv = kt * 64 + ni * 16 + fg * 4 + r;
            if (kv > qrow[mi]) s[mi][ni][r] = -1e30f;
          }
    }

    // in-register online softmax (per mi: 15 fmax + 2 shfl; sum likewise)
#pragma unroll
    for (int mi = 0; mi < 2; mi++) {
      float v01 = fmaxf(fmaxf(fmaxf(s[mi][0][0], s[mi][0][1]),
                              fmaxf(s[mi][0][2], s[mi][0][3])),
                        fmaxf(fmaxf(s[mi][1][0], s[mi][1][1]),
                              fmaxf(s[mi][1][2], s[mi][1][3])));
      float v23 = fmaxf(fmaxf(fmaxf(s[mi][2][0], s[mi][2][1]),
                              fmaxf(s[mi][2][2], s[mi][2][3])),
                        fmaxf(fmaxf(s[mi][3][0], s[mi][3][1]),
                              fmaxf(s[mi][3][2], s[mi][3][3])));
      float v = fmaxf(v01, v23);
      v = fmaxf(v, __shfl_xor(v, 16, 64));
      v = fmaxf(v, __shfl_xor(v, 32, 64));
      float mn = fmaxf(mrow[mi], v);
      float scl = exp2f(mrow[mi] - mn);
      mrow[mi] = mn;
      float rs = 0.f;
#pragma unroll
      for (int ni = 0; ni < 4; ni++)
#pragma unroll
        for (int r = 0; r < 4; r++) {
          float p = exp2f(s[mi][ni][r] - mn);
          s[mi][ni][r] = p;
          rs += p;
        }
      rs += __shfl_xor(rs, 16, 64);
      rs += __shfl_xor(rs, 32, 64);
      lrow[mi] = lrow[mi] * scl + rs;
#pragma unroll
      for (int di = 0; di < 4; di++)
#pragma unroll
        for (int r = 0; r < 4; r++) oacc[mi][di][r] *= scl;
    }

    // pack P to bf16 pairs: pk[mi][ni][h] = (bf16(s[2h]) | bf16(s[2h+1])<<16)
    unsigned pk[2][4][2];
#pragma unroll
    for (int mi = 0; mi < 2; mi++)
#pragma unroll
      for (int ni = 0; ni < 4; ni++) {
        pk[mi][ni][0] = cvt_pk_bf16(s[mi][ni][0], s[mi][ni][1]);
        pk[mi][ni][1] = cvt_pk_bf16(s[mi][ni][2], s[mi][ni][3]);
      }

    // PV: O^T += V^T * P^T (A = V^T frag, B = P^T frag rebuilt via bpermute)
#pragma unroll
    for (int ks = 0; ks < 2; ks++) {
      bf16x8 pb[2];
#pragma unroll
      for (int mi = 0; mi < 2; mi++) {
        int n0 = 2 * ks, n1 = 2 * ks + 1;
        int lo, hi;
        uint4v u;
        lo = __builtin_amdgcn_ds_bpermute(addr0, (int)pk[mi][n0][0]);
        hi = __builtin_amdgcn_ds_bpermute(addr0, (int)pk[mi][n1][0]);
        u.x = hiSel ? (unsigned)hi : (unsigned)lo;
        lo = __builtin_amdgcn_ds_bpermute(addr0, (int)pk[mi][n0][1]);
        hi = __builtin_amdgcn_ds_bpermute(addr0, (int)pk[mi][n1][1]);
        u.y = hiSel ? (unsigned)hi : (unsigned)lo;
        lo = __builtin_amdgcn_ds_bpermute(addr1, (int)pk[mi][n0][0]);
        hi = __builtin_amdgcn_ds_bpermute(addr1, (int)pk[mi][n1][0]);
        u.z = hiSel ? (unsigned)hi : (unsigned)lo;
        lo = __builtin_amdgcn_ds_bpermute(addr1, (int)pk[mi][n0][1]);
        hi = __builtin_amdgcn_ds_bpermute(addr1, (int)pk[mi][n1][1]);
        u.w = hiSel ? (unsigned)hi : (unsigned)lo;
        pb[mi] = __builtin_bit_cast(bf16x8, u);
      }
#pragma unroll
      for (int di = 0; di < 4; di++) {
        bf16x8 vf = *(const bf16x8*)(vbuf + (di * 16 + fr) * 144 +
                                     (ks * 4 + fg) * 16);
#pragma unroll
        for (int mi = 0; mi < 2; mi++)
          oacc[mi][di] = __builtin_amdgcn_mfma_f32_16x16x32_bf16(vf, pb[mi],
                                                                 oacc[mi][di], 0, 0, 0);
      }
    }
    __syncthreads();
  }

  // epilogue: O^T[d][q] -> out[q][d], 4 consecutive d per (mi,di) -> ushort4
#pragma unroll
  for (int mi = 0; mi < 2; mi++) {
    float inv = 1.f / lrow[mi];
    int q = qrow[mi];
#pragma unroll
    for (int di = 0; di < 4; di++) {
      ushort4 o;
      o.x = f2bf(oacc[mi][di][0] * inv);
      o.y = f2bf(oacc[mi][di][1] * inv);
      o.z = f2bf(oacc[mi][di][2] * inv);
      o.w = f2bf(oacc[mi][di][3] * inv);
      *(ushort4*)(qbase + (size_t)q * HD_ + di * 16 + fg * 4) = o;
    }
  }
}

// ---------------- GEMM2: out = attn(head-major bf16) @ wprojT^T + b_proj (f32)

__global__ __launch_bounds__(256, 2) void gemm_proj(
    const unsigned short* __restrict__ Ahm, const unsigned short* __restrict__ Bt,
    const float* __restrict__ bias, float* __restrict__ outf) {
  __shared__ __align__(16) unsigned short la[128 * 32];
  __shared__ __align__(16) unsigned short lb[128 * 32];
  const int tid = threadIdx.x, lane = tid & 63, wave = tid >> 6;
  const int wr = wave >> 1, wc = wave & 1;
  const int m0 = blockIdx.y * 128, n0 = blockIdx.x * 128;
  const int fr = lane & 15, fg = lane >> 4;
  const int r4 = tid >> 2, s4 = tid & 3;

  f32x4 acc[4][4] = {};

  for (int k0 = 0; k0 < C_; k0 += 32) {
    int head = k0 >> 6, off = k0 & 63;
    {
      int row = m0 + r4;
      async16(Ahm + (((size_t)(row >> 11) * NH_ + head) * T_ + (row & 2047)) * HD_ +
                  off + s4 * 8,
              (char*)la + wave * 1024);
      row = m0 + 64 + r4;
      async16(Ahm + (((size_t)(row >> 11) * NH_ + head) * T_ + (row & 2047)) * HD_ +
                  off + s4 * 8,
              (char*)la + 4096 + wave * 1024);
    }
    async16(Bt + (size_t)(n0 + r4) * C_ + k0 + s4 * 8, (char*)lb + wave * 1024);
    async16(Bt + (size_t)(n0 + 64 + r4) * C_ + k0 + s4 * 8,
            (char*)lb + 4096 + wave * 1024);
    __syncthreads();

    bf16x8 af[4], bfr[4];
#pragma unroll
    for (int mi = 0; mi < 4; mi++) {
      int row = wr * 64 + mi * 16 + fr;
      af[mi] = *(const bf16x8*)((const char*)la + row * 64 + fg * 16);
    }
#pragma unroll
    for (int ni = 0; ni < 4; ni++) {
      int row = wc * 64 + ni * 16 + fr;
      bfr[ni] = *(const bf16x8*)((const char*)lb + row * 64 + fg * 16);
    }
#pragma unroll
    for (int mi = 0; mi < 4; mi++)
#pragma unroll
      for (int ni = 0; ni < 4; ni++)
        acc[mi][ni] = __builtin_amdgcn_mfma_f32_16x16x32_bf16(af[mi], bfr[ni],
                                                              acc[mi][ni], 0, 0, 0);
    __syncthreads();
  }

#pragma unroll
  for (int mi = 0; mi < 4; mi++)
#pragma unroll
    for (int ni = 0; ni < 4; ni++) {
      int col = n0 + wc * 64 + ni * 16 + fr;
      float bv = bias[col];
#pragma unroll
      for (int r = 0; r < 4; r++) {
        int row = m0 + wr * 64 + mi * 16 + fg * 4 + r;
        outf[(size_t)row * C_ + col] = acc[mi][ni][r] + bv;
      }
    }
}

// ---------------- launch ----------------

extern "C" void kernel_launch(void* const* d_in, const int* in_sizes, int n_in,
                              void* d_out, int out_size, void* d_ws, size_t ws_size,
                              hipStream_t stream) {
  (void)in_sizes; (void)n_in; (void)out_size;
  const float* x      = (const float*)d_in[0];
  const float* w_attn = (const float*)d_in[1];
  const float* b_attn = (const float*)d_in[2];
  const float* w_proj = (const float*)d_in[3];
  const float* b_proj = (const float*)d_in[4];
  float* out = (float*)d_out;
  char* ws = (char*)d_ws;

  // ws layout, 58.7 MiB base:
  unsigned short* qws    = (unsigned short*)(ws);              // [b,h,t,d]; becomes attn out
  unsigned short* kws    = (unsigned short*)(ws + 16777216);   // [b,h,t,d]
  unsigned short* vtws   = (unsigned short*)(ws + 33554432);   // [b,h,d,t]
  unsigned short* wqkvT  = (unsigned short*)(ws + 50331648);   // [3072][1024] bf16
  unsigned short* wprojT = (unsigned short*)(ws + 56623104);   // [1024][1024] bf16
  // xb (x as bf16, 16.8 MB): ws tail if it fits, else scratch inside d_out
  // (d_out is fully overwritten by gemm_proj at the end; stream-ordered).
  size_t xb_off = 58720256;
  unsigned short* xb = (ws_size >= xb_off + (size_t)M_TOT * C_ * 2)
                           ? (unsigned short*)(ws + xb_off)
                           : (unsigned short*)d_out;

  f32_to_bf16_k<<<2048, 256, 0, stream>>>(x, xb, M_TOT * C_);
  transpose_conv_k<<<dim3(96, 32), 256, 0, stream>>>(w_attn, wqkvT, C_, 3 * C_);
  transpose_conv_k<<<dim3(32, 32), 256, 0, stream>>>(w_proj, wprojT, C_, C_);
  gemm_qkv<<<dim3(24, 64), 256, 0, stream>>>(xb, wqkvT, b_attn, qws, kws, vtws);
  attn_k<<<dim3(16, 64), 256, 0, stream>>>(qws, kws, vtws);
  gemm_proj<<<dim3(8, 64), 256, 0, stream>>>(qws, wprojT, b_proj, out);
}

// Round 8
// 295.584 us; speedup vs baseline: 1.8052x; 1.2525x over previous
//
#include <hip/hip_runtime.h>

#define T_ 2048
#define C_ 1024
#define NH_ 16
#define HD_ 64
#define M_TOT 8192  // B*T

typedef __bf16 bf16x8 __attribute__((ext_vector_type(8)));
typedef float f32x4 __attribute__((ext_vector_type(4)));
typedef unsigned short ushort8 __attribute__((ext_vector_type(8)));
typedef unsigned int uint4v __attribute__((ext_vector_type(4)));

__device__ __forceinline__ unsigned short f2bf(float f) {
  union { float f; unsigned u; } v; v.f = f;
  unsigned r = v.u + 0x7fffu + ((v.u >> 16) & 1u);
  return (unsigned short)(r >> 16);
}

__device__ __forceinline__ void async16(const void* g, void* l) {
  __builtin_amdgcn_global_load_lds(
      (__attribute__((address_space(1))) void*)g,
      (__attribute__((address_space(3))) void*)l, 16, 0, 0);
}

// pack two f32 -> dword of 2 bf16 (lo in bits[15:0])
__device__ __forceinline__ unsigned cvt_pk_bf16(float lo, float hi) {
  unsigned d;
  asm volatile("v_cvt_pk_bf16_f32 %0, %1, %2" : "=v"(d) : "v"(lo), "v"(hi));
  return d;
}

// ---------------- prep kernels ----------------

__global__ void f32_to_bf16_k(const float* __restrict__ in,
                              unsigned short* __restrict__ out, int n) {
  int i = (blockIdx.x * blockDim.x + threadIdx.x) * 4;
  int stride = gridDim.x * blockDim.x * 4;
  for (; i < n; i += stride) {
    float4 v = *(const float4*)(in + i);
    ushort4 o;
    o.x = f2bf(v.x); o.y = f2bf(v.y); o.z = f2bf(v.z); o.w = f2bf(v.w);
    *(ushort4*)(out + i) = o;
  }
}

// out[c][r] = bf16(in[r][c]); grid (Cc/32, R/32), 256 thr
__global__ void transpose_conv_k(const float* __restrict__ in,
                                 unsigned short* __restrict__ out, int R, int Cc) {
  __shared__ float tile[32][33];
  int c0 = blockIdx.x * 32, r0 = blockIdx.y * 32;
  int lx = threadIdx.x & 31, ly = threadIdx.x >> 5;
#pragma unroll
  for (int j = 0; j < 32; j += 8)
    tile[ly + j][lx] = in[(size_t)(r0 + ly + j) * Cc + c0 + lx];
  __syncthreads();
#pragma unroll
  for (int j = 0; j < 32; j += 8)
    out[(size_t)(c0 + ly + j) * R + r0 + lx] = f2bf(tile[lx][ly + j]);
}

// ---------------- GEMM1: qkv = xb(bf16) @ wqkvT^T + b; scatter Q,K (head-major)
// and V transposed [b,h,d,t]. 1D grid of 1536, chunked XCD swizzle.

__global__ __launch_bounds__(256, 2) void gemm_qkv(
    const unsigned short* __restrict__ A, const unsigned short* __restrict__ Bt,
    const float* __restrict__ bias, unsigned short* __restrict__ qw,
    unsigned short* __restrict__ kw, unsigned short* __restrict__ vtw) {
  __shared__ __align__(16) unsigned short la[128 * 32];
  __shared__ __align__(16) unsigned short lb[128 * 32];
  const int tid = threadIdx.x, lane = tid & 63, wave = tid >> 6;
  const int wr = wave >> 1, wc = wave & 1;
  // chunked XCD swizzle: each XCD gets 192 consecutive wg (8 m-rows x 24 n)
  const int raw = blockIdx.x;
  const int wg = (raw & 7) * 192 + (raw >> 3);
  const int m0 = (wg / 24) * 128, n0 = (wg % 24) * 128;
  const int fr = lane & 15, fg = lane >> 4;
  const int r4 = tid >> 2, s4 = tid & 3;

  f32x4 acc[4][4] = {};

  for (int k0 = 0; k0 < C_; k0 += 32) {
    async16(A + (size_t)(m0 + r4) * C_ + k0 + s4 * 8, (char*)la + wave * 1024);
    async16(A + (size_t)(m0 + 64 + r4) * C_ + k0 + s4 * 8,
            (char*)la + 4096 + wave * 1024);
    async16(Bt + (size_t)(n0 + r4) * C_ + k0 + s4 * 8, (char*)lb + wave * 1024);
    async16(Bt + (size_t)(n0 + 64 + r4) * C_ + k0 + s4 * 8,
            (char*)lb + 4096 + wave * 1024);
    __syncthreads();

    bf16x8 af[4], bfr[4];
#pragma unroll
    for (int mi = 0; mi < 4; mi++) {
      int row = wr * 64 + mi * 16 + fr;
      af[mi] = *(const bf16x8*)((const char*)la + row * 64 + fg * 16);
    }
#pragma unroll
    for (int ni = 0; ni < 4; ni++) {
      int row = wc * 64 + ni * 16 + fr;
      bfr[ni] = *(const bf16x8*)((const char*)lb + row * 64 + fg * 16);
    }
#pragma unroll
    for (int mi = 0; mi < 4; mi++)
#pragma unroll
      for (int ni = 0; ni < 4; ni++)
        acc[mi][ni] = __builtin_amdgcn_mfma_f32_16x16x32_bf16(af[mi], bfr[ni],
                                                              acc[mi][ni], 0, 0, 0);
    __syncthreads();
  }

  // epilogue: C/D layout col=lane&15, row=(lane>>4)*4+r (m89-verified)
#pragma unroll
  for (int mi = 0; mi < 4; mi++)
#pragma unroll
    for (int ni = 0; ni < 4; ni++) {
      int col = n0 + wc * 64 + ni * 16 + fr;
      float bv = bias[col];
      int which = col >> 10, within = col & 1023;
      int h = within >> 6, hd = within & 63;
#pragma unroll
      for (int r = 0; r < 4; r++) {
        int row = m0 + wr * 64 + mi * 16 + fg * 4 + r;
        int b = row >> 11, t = row & 2047;
        unsigned short u = f2bf(acc[mi][ni][r] + bv);
        if (which == 0)
          qw[(((size_t)b * NH_ + h) * T_ + t) * HD_ + hd] = u;
        else if (which == 1)
          kw[(((size_t)b * NH_ + h) * T_ + t) * HD_ + hd] = u;
        else
          vtw[(((size_t)b * NH_ + h) * HD_ + hd) * T_ + t] = u;
      }
    }
}

// ---------------- flash attention (swapped-operand, QBLK=64): 2048 blocks, 4 waves.
// S^T = mfma(K,Q): lane owns q-col -> in-register softmax; P in regs via
// cvt_pk + ds_bpermute; PV: O^T = mfma(V^T, P^T). bh->XCD locality swizzle.

__global__ __launch_bounds__(256, 2) void attn_k(
    unsigned short* __restrict__ qws, const unsigned short* __restrict__ kws,
    const unsigned short* __restrict__ vtws) {
  __shared__ __align__(16) char kbuf[64 * 144];
  __shared__ __align__(16) char vbuf[64 * 144];
  const int tid = threadIdx.x, lane = tid & 63, wave = tid >> 6;
  // swizzle: XCD (raw%8) owns 8 bh; within XCD, qb descending (LPT)
  const int raw = blockIdx.x;
  const int slot = raw >> 3;
  const int bh = (raw & 7) * 8 + (slot & 7);
  const int qb = 31 - (slot >> 3);
  const int fr = lane & 15, fg = lane >> 4;
  unsigned short* qbase = qws + (size_t)bh * T_ * HD_;
  const unsigned short* kbase = kws + (size_t)bh * T_ * HD_;
  const unsigned short* vbase = vtws + (size_t)bh * HD_ * T_;  // [d][t]
  const int r0 = tid >> 3, sl = tid & 7;

  // Q fragments (B-operand: col=q=fr, k=d chunk fg)
  bf16x8 qf[2];
#pragma unroll
  for (int ks = 0; ks < 2; ks++)
    qf[ks] = *(const bf16x8*)(qbase + (size_t)(qb * 64 + wave * 16 + fr) * HD_ +
                              ks * 32 + fg * 8);
  const int qrow = qb * 64 + wave * 16 + fr;

  f32x4 oacc[4] = {};  // O^T: col=q=fr, row d = di*16+fg*4+r
  float mrow = -1e30f, lrow = 0.f;

  const float SC = 0.125f * 1.44269504f;  // 1/sqrt(64) * log2(e)

  // bpermute addresses for P^T fragment rebuild
  const int addr0 = (fr + 16 * ((2 * fg) & 3)) * 4;
  const int addr1 = (fr + 16 * ((2 * fg + 1) & 3)) * 4;
  const bool hiSel = (fg >> 1) != 0;

  // register prefetch of K/V tile (T14)
  ushort8 ka, kb2, va, vb2;
  {
    ka  = *(const ushort8*)(kbase + (size_t)(r0) * HD_ + sl * 8);
    kb2 = *(const ushort8*)(kbase + (size_t)(32 + r0) * HD_ + sl * 8);
    va  = *(const ushort8*)(vbase + (size_t)r0 * T_ + sl * 8);
    vb2 = *(const ushort8*)(vbase + (size_t)(32 + r0) * T_ + sl * 8);
  }

  for (int kt = 0; kt <= qb; kt++) {
    // write staged regs to LDS
    *(ushort8*)(kbuf + r0 * 144 + sl * 16) = ka;
    *(ushort8*)(kbuf + (32 + r0) * 144 + sl * 16) = kb2;
    *(ushort8*)(vbuf + r0 * 144 + sl * 16) = va;
    *(ushort8*)(vbuf + (32 + r0) * 144 + sl * 16) = vb2;
    __syncthreads();

    // issue next tile's loads (hidden under compute)
    if (kt < qb) {
      int kn = kt + 1;
      ka  = *(const ushort8*)(kbase + (size_t)(kn * 64 + r0) * HD_ + sl * 8);
      kb2 = *(const ushort8*)(kbase + (size_t)(kn * 64 + 32 + r0) * HD_ + sl * 8);
      va  = *(const ushort8*)(vbase + (size_t)r0 * T_ + kn * 64 + sl * 8);
      vb2 = *(const ushort8*)(vbase + (size_t)(32 + r0) * T_ + kn * 64 + sl * 8);
    }

    // S^T = K Q^T : s[ni][r] = S[kv = kt*64+ni*16+fg*4+r][q = qrow]
    f32x4 s[4] = {};
#pragma unroll
    for (int ni = 0; ni < 4; ni++)
#pragma unroll
      for (int ks = 0; ks < 2; ks++) {
        bf16x8 kf = *(const bf16x8*)(kbuf + (ni * 16 + fr) * 144 + (ks * 4 + fg) * 16);
        s[ni] = __builtin_amdgcn_mfma_f32_16x16x32_bf16(kf, qf[ks], s[ni], 0, 0, 0);
      }

    // scale (+ causal mask on the diagonal tile)
#pragma unroll
    for (int ni = 0; ni < 4; ni++)
#pragma unroll
      for (int r = 0; r < 4; r++) s[ni][r] *= SC;
    if (kt == qb) {
#pragma unroll
      for (int ni = 0; ni < 4; ni++)
#pragma unroll
        for (int r = 0; r < 4; r++) {
          int kv = kt * 64 + ni * 16 + fg * 4 + r;
          if (kv > qrow) s[ni][r] = -1e30f;
        }
    }

    // in-register online softmax (15 fmax + 2 shfl; sum likewise)
    {
      float v01 = fmaxf(fmaxf(fmaxf(s[0][0], s[0][1]), fmaxf(s[0][2], s[0][3])),
                        fmaxf(fmaxf(s[1][0], s[1][1]), fmaxf(s[1][2], s[1][3])));
      float v23 = fmaxf(fmaxf(fmaxf(s[2][0], s[2][1]), fmaxf(s[2][2], s[2][3])),
                        fmaxf(fmaxf(s[3][0], s[3][1]), fmaxf(s[3][2], s[3][3])));
      float v = fmaxf(v01, v23);
      v = fmaxf(v, __shfl_xor(v, 16, 64));
      v = fmaxf(v, __shfl_xor(v, 32, 64));
      float mn = fmaxf(mrow, v);
      float scl = exp2f(mrow - mn);
      mrow = mn;
      float rs = 0.f;
#pragma unroll
      for (int ni = 0; ni < 4; ni++)
#pragma unroll
        for (int r = 0; r < 4; r++) {
          float p = exp2f(s[ni][r] - mn);
          s[ni][r] = p;
          rs += p;
        }
      rs += __shfl_xor(rs, 16, 64);
      rs += __shfl_xor(rs, 32, 64);
      lrow = lrow * scl + rs;
#pragma unroll
      for (int di = 0; di < 4; di++)
#pragma unroll
        for (int r = 0; r < 4; r++) oacc[di][r] *= scl;
    }

    // pack P to bf16 pairs
    unsigned pk[4][2];
#pragma unroll
    for (int ni = 0; ni < 4; ni++) {
      pk[ni][0] = cvt_pk_bf16(s[ni][0], s[ni][1]);
      pk[ni][1] = cvt_pk_bf16(s[ni][2], s[ni][3]);
    }

    // PV: O^T += V^T * P^T (A = V^T frag, B = P^T frag rebuilt via bpermute)
#pragma unroll
    for (int ks = 0; ks < 2; ks++) {
      int n0i = 2 * ks, n1i = 2 * ks + 1;
      int lo, hi;
      uint4v u;
      lo = __builtin_amdgcn_ds_bpermute(addr0, (int)pk[n0i][0]);
      hi = __builtin_amdgcn_ds_bpermute(addr0, (int)pk[n1i][0]);
      u.x = hiSel ? (unsigned)hi : (unsigned)lo;
      lo = __builtin_amdgcn_ds_bpermute(addr0, (int)pk[n0i][1]);
      hi = __builtin_amdgcn_ds_bpermute(addr0, (int)pk[n1i][1]);
      u.y = hiSel ? (unsigned)hi : (unsigned)lo;
      lo = __builtin_amdgcn_ds_bpermute(addr1, (int)pk[n0i][0]);
      hi = __builtin_amdgcn_ds_bpermute(addr1, (int)pk[n1i][0]);
      u.z = hiSel ? (unsigned)hi : (unsigned)lo;
      lo = __builtin_amdgcn_ds_bpermute(addr1, (int)pk[n0i][1]);
      hi = __builtin_amdgcn_ds_bpermute(addr1, (int)pk[n1i][1]);
      u.w = hiSel ? (unsigned)hi : (unsigned)lo;
      bf16x8 pb = __builtin_bit_cast(bf16x8, u);
#pragma unroll
      for (int di = 0; di < 4; di++) {
        bf16x8 vf = *(const bf16x8*)(vbuf + (di * 16 + fr) * 144 +
                                     (ks * 4 + fg) * 16);
        oacc[di] = __builtin_amdgcn_mfma_f32_16x16x32_bf16(vf, pb, oacc[di], 0, 0, 0);
      }
    }
    __syncthreads();
  }

  // epilogue: O^T[d][q] -> out[q][d]
  {
    float inv = 1.f / lrow;
#pragma unroll
    for (int di = 0; di < 4; di++) {
      ushort4 o;
      o.x = f2bf(oacc[di][0] * inv);
      o.y = f2bf(oacc[di][1] * inv);
      o.z = f2bf(oacc[di][2] * inv);
      o.w = f2bf(oacc[di][3] * inv);
      *(ushort4*)(qbase + (size_t)qrow * HD_ + di * 16 + fg * 4) = o;
    }
  }
}

// ---------------- GEMM2: out = attn(head-major bf16) @ wprojT^T + b_proj (f32)
// 1D grid of 512, chunked XCD swizzle.

__global__ __launch_bounds__(256, 2) void gemm_proj(
    const unsigned short* __restrict__ Ahm, const unsigned short* __restrict__ Bt,
    const float* __restrict__ bias, float* __restrict__ outf) {
  __shared__ __align__(16) unsigned short la[128 * 32];
  __shared__ __align__(16) unsigned short lb[128 * 32];
  const int tid = threadIdx.x, lane = tid & 63, wave = tid >> 6;
  const int wr = wave >> 1, wc = wave & 1;
  const int raw = blockIdx.x;
  const int wg = (raw & 7) * 64 + (raw >> 3);
  const int m0 = (wg >> 3) * 128, n0 = (wg & 7) * 128;
  const int fr = lane & 15, fg = lane >> 4;
  const int r4 = tid >> 2, s4 = tid & 3;

  f32x4 acc[4][4] = {};

  for (int k0 = 0; k0 < C_; k0 += 32) {
    int head = k0 >> 6, off = k0 & 63;
    {
      int row = m0 + r4;
      async16(Ahm + (((size_t)(row >> 11) * NH_ + head) * T_ + (row & 2047)) * HD_ +
                  off + s4 * 8,
              (char*)la + wave * 1024);
      row = m0 + 64 + r4;
      async16(Ahm + (((size_t)(row >> 11) * NH_ + head) * T_ + (row & 2047)) * HD_ +
                  off + s4 * 8,
              (char*)la + 4096 + wave * 1024);
    }
    async16(Bt + (size_t)(n0 + r4) * C_ + k0 + s4 * 8, (char*)lb + wave * 1024);
    async16(Bt + (size_t)(n0 + 64 + r4) * C_ + k0 + s4 * 8,
            (char*)lb + 4096 + wave * 1024);
    __syncthreads();

    bf16x8 af[4], bfr[4];
#pragma unroll
    for (int mi = 0; mi < 4; mi++) {
      int row = wr * 64 + mi * 16 + fr;
      af[mi] = *(const bf16x8*)((const char*)la + row * 64 + fg * 16);
    }
#pragma unroll
    for (int ni = 0; ni < 4; ni++) {
      int row = wc * 64 + ni * 16 + fr;
      bfr[ni] = *(const bf16x8*)((const char*)lb + row * 64 + fg * 16);
    }
#pragma unroll
    for (int mi = 0; mi < 4; mi++)
#pragma unroll
      for (int ni = 0; ni < 4; ni++)
        acc[mi][ni] = __builtin_amdgcn_mfma_f32_16x16x32_bf16(af[mi], bfr[ni],
                                                              acc[mi][ni], 0, 0, 0);
    __syncthreads();
  }

#pragma unroll
  for (int mi = 0; mi < 4; mi++)
#pragma unroll
    for (int ni = 0; ni < 4; ni++) {
      int col = n0 + wc * 64 + ni * 16 + fr;
      float bv = bias[col];
#pragma unroll
      for (int r = 0; r < 4; r++) {
        int row = m0 + wr * 64 + mi * 16 + fg * 4 + r;
        outf[(size_t)row * C_ + col] = acc[mi][ni][r] + bv;
      }
    }
}

// ---------------- launch ----------------

extern "C" void kernel_launch(void* const* d_in, const int* in_sizes, int n_in,
                              void* d_out, int out_size, void* d_ws, size_t ws_size,
                              hipStream_t stream) {
  (void)in_sizes; (void)n_in; (void)out_size;
  const float* x      = (const float*)d_in[0];
  const float* w_attn = (const float*)d_in[1];
  const float* b_attn = (const float*)d_in[2];
  const float* w_proj = (const float*)d_in[3];
  const float* b_proj = (const float*)d_in[4];
  float* out = (float*)d_out;
  char* ws = (char*)d_ws;

  // ws layout, 58.7 MiB base:
  unsigned short* qws    = (unsigned short*)(ws);              // [b,h,t,d]; becomes attn out
  unsigned short* kws    = (unsigned short*)(ws + 16777216);   // [b,h,t,d]
  unsigned short* vtws   = (unsigned short*)(ws + 33554432);   // [b,h,d,t]
  unsigned short* wqkvT  = (unsigned short*)(ws + 50331648);   // [3072][1024] bf16
  unsigned short* wprojT = (unsigned short*)(ws + 56623104);   // [1024][1024] bf16
  // xb (x as bf16, 16.8 MB): ws tail if it fits, else scratch inside d_out
  // (d_out is fully overwritten by gemm_proj at the end; stream-ordered).
  size_t xb_off = 58720256;
  unsigned short* xb = (ws_size >= xb_off + (size_t)M_TOT * C_ * 2)
                           ? (unsigned short*)(ws + xb_off)
                           : (unsigned short*)d_out;

  f32_to_bf16_k<<<2048, 256, 0, stream>>>(x, xb, M_TOT * C_);
  transpose_conv_k<<<dim3(96, 32), 256, 0, stream>>>(w_attn, wqkvT, C_, 3 * C_);
  transpose_conv_k<<<dim3(32, 32), 256, 0, stream>>>(w_proj, wprojT, C_, C_);
  gemm_qkv<<<1536, 256, 0, stream>>>(xb, wqkvT, b_attn, qws, kws, vtws);
  attn_k<<<2048, 256, 0, stream>>>(qws, kws, vtws);
  gemm_proj<<<512, 256, 0, stream>>>(qws, wprojT, b_proj, out);
}